// Round 1
// baseline (413.033 us; speedup 1.0000x reference)
//
#include <hip/hip_runtime.h>
#include <hip/hip_bf16.h>
#include <math.h>

// attr = labels(1024x50000 f32) @ weight(50000x300 f32); out = attr/(||attr||+1e-7)
// k1: weight -> Wt[n][k] bf16 (n padded to 320) -- LDS transpose
// k2: split-K MFMA GEMM, BM=64 BN=320 BK=32, DOUBLE-BUFFERED LDS,
//     single barrier per K-step (staging writes overlap MFMA issue).
//     NON-ATOMIC per-split partials (atomic fallback if ws too small)
// k3: reduce partials over splits + row L2 normalize (fused)
typedef __bf16 bf16;
typedef bf16 bf16x8 __attribute__((ext_vector_type(8)));
typedef bf16 bf16x4 __attribute__((ext_vector_type(4)));
typedef float f32x4 __attribute__((ext_vector_type(4)));

constexpr int Mdim = 1024;
constexpr int Kdim = 50000;
constexpr int Ndim = 300;
constexpr int NP   = 320;

constexpr int BM = 64, BN = 320, BK = 32;
constexpr int BKP = 40;            // LDS k-stride (bf16): 80 B rows, 16B-aligned,
                                   // bank stride 20 dwords -> 2-way max (free)
constexpr int MT = Mdim / BM;      // 16 m-tiles

// ---------------- k1: transpose + convert -----------------------------------
constexpr int TK = 64;
constexpr int TS = 301;
__global__ __launch_bounds__(256) void transpose_w(const float* __restrict__ W,
                                                   bf16* __restrict__ Wt)
{
    __shared__ bf16 tile[TK * TS];
    const int k0 = blockIdx.x * TK;
    const int t  = threadIdx.x;

    for (int c = t; c < 64 * 75; c += 256) {
        const int kk = c / 75;
        const int ch = c % 75;
        const int k  = k0 + kk;
        float4 v = make_float4(0.f, 0.f, 0.f, 0.f);
        if (k < Kdim) v = *(const float4*)(W + (size_t)k * Ndim + ch * 4);
        bf16* p = &tile[kk * TS + ch * 4];
        p[0] = (bf16)v.x; p[1] = (bf16)v.y; p[2] = (bf16)v.z; p[3] = (bf16)v.w;
    }
    __syncthreads();
    for (int c = t; c < NP * 8; c += 256) {
        const int n  = c >> 3;
        const int ch = c & 7;
        const int k  = k0 + ch * 8;
        if (k + 8 <= Kdim) {
            bf16x8 v;
#pragma unroll
            for (int e = 0; e < 8; ++e) v[e] = (bf16)0.0f;
            if (n < Ndim) {
#pragma unroll
                for (int j = 0; j < 8; ++j) v[j] = tile[(ch * 8 + j) * TS + n];
            }
            *(bf16x8*)(Wt + (size_t)n * Kdim + k) = v;
        }
    }
}

// ---------------- k2: split-K MFMA GEMM (dbuf, 1 barrier/step) --------------
// ATOMIC=false: out = P, partials at P[ks][Mdim][NP] (plain stores)
// ATOMIC=true : out = Cacc[Mdim][NP] (atomicAdd), Cacc pre-zeroed
template<int SPLIT, int SEGLEN, bool ATOMIC>
__global__ __launch_bounds__(512, 4) void gemm_kernel(const float* __restrict__ A,
                                                      const bf16* __restrict__ Wt,
                                                      float* __restrict__ out)
{
    __shared__ bf16 As[2][BM * BKP];   // 2 x  5120 B
    __shared__ bf16 Bs[2][BN * BKP];   // 2 x 25600 B  (61440 total -> 2 blocks/CU)

    const int bx   = blockIdx.x;
    const int mt   = bx & (MT - 1);
    const int ks   = bx >> 4;
    const int m0   = mt * BM;
    const int kbeg = ks * SEGLEN;
    const int kend = min(kbeg + SEGLEN, Kdim);

    const int t    = threadIdx.x;
    const int lane = t & 63;
    const int wave = t >> 6;         // 0..7 as 2m x 4n
    const int wm   = wave >> 2;
    const int wn   = wave & 3;
    const int lm   = lane & 15;
    const int lq   = lane >> 4;      // 0..3 -> k = lq*8

    // A staging: 512 threads cover 64 rows x 32 k exactly (1 float4 each)
    const int arow = t >> 3;
    const int acol = (t & 7) * 4;
    const float* aptr = A + (size_t)(m0 + arow) * Kdim + acol;

    // B staging: 512 threads x 5 chunks of 4 bf16 cover 320 rows x 32 k
    int brow[5], bcol[5];
#pragma unroll
    for (int i = 0; i < 5; ++i) {
        const int c = t + 512 * i;
        brow[i] = c >> 3;
        bcol[i] = (c & 7) * 4;
    }

    float4 af;
    uint2  bfr[5];

    auto load_tiles = [&](int k0) {
        af = (k0 + acol + 4 <= kend) ? *(const float4*)(aptr + k0)
                                     : make_float4(0.f, 0.f, 0.f, 0.f);
#pragma unroll
        for (int i = 0; i < 5; ++i) {
            const int kk = k0 + bcol[i];
            bfr[i] = (kk + 4 <= kend)
                   ? *(const uint2*)(Wt + (size_t)brow[i] * Kdim + kk)
                   : make_uint2(0u, 0u);
        }
    };
    auto store_tiles = [&](int buf) {
        bf16x4 v;
        v[0] = (bf16)af.x; v[1] = (bf16)af.y; v[2] = (bf16)af.z; v[3] = (bf16)af.w;
        *(bf16x4*)(&As[buf][arow * BKP + acol]) = v;
#pragma unroll
        for (int i = 0; i < 5; ++i)
            *(uint2*)(&Bs[buf][brow[i] * BKP + bcol[i]]) = bfr[i];
    };

    f32x4 acc[2][5] = {};

    load_tiles(kbeg);
    store_tiles(0);
    __syncthreads();

    int cur = 0;
    for (int k0 = kbeg; k0 < kend; k0 += BK) {
        const bool more = (k0 + BK < kend);
        if (more) load_tiles(k0 + BK);      // global loads issue first
        bf16x8 a[2], b[5];
#pragma unroll
        for (int i = 0; i < 2; ++i)
            a[i] = *(const bf16x8*)(&As[cur][(wm * 32 + i * 16 + lm) * BKP + lq * 8]);
#pragma unroll
        for (int j = 0; j < 5; ++j)
            b[j] = *(const bf16x8*)(&Bs[cur][(wn * 80 + j * 16 + lm) * BKP + lq * 8]);
#pragma unroll
        for (int i = 0; i < 2; ++i)
#pragma unroll
            for (int j = 0; j < 5; ++j)
                acc[i][j] = __builtin_amdgcn_mfma_f32_16x16x32_bf16(a[i], b[j], acc[i][j], 0, 0, 0);
        if (more) store_tiles(cur ^ 1);     // waits loads, writes OTHER buffer
        __syncthreads();                    // single barrier per step
        cur ^= 1;
    }

    // C/D layout: col=lane&15, row=(lane>>4)*4+r  [learn_hip m89]
    const int col0 = wn * 80 + lm;
    const int rloc = wm * 32 + lq * 4;
    if (ATOMIC) {
#pragma unroll
        for (int i = 0; i < 2; ++i)
#pragma unroll
            for (int j = 0; j < 5; ++j)
#pragma unroll
                for (int r = 0; r < 4; ++r)
                    atomicAdd(&out[(size_t)(m0 + rloc + i * 16 + r) * NP + col0 + j * 16],
                              acc[i][j][r]);
    } else {
        float* P = out + (size_t)ks * Mdim * NP;
#pragma unroll
        for (int i = 0; i < 2; ++i)
#pragma unroll
            for (int j = 0; j < 5; ++j)
#pragma unroll
                for (int r = 0; r < 4; ++r)
                    P[(size_t)(m0 + rloc + i * 16 + r) * NP + col0 + j * 16] = acc[i][j][r];
    }
}

// ---------------- k3a: reduce partials + L2 normalize (partial path) --------
__global__ __launch_bounds__(320) void reduce_norm_k(const float* __restrict__ P,
                                                     float* __restrict__ out,
                                                     int split)
{
    const int b = blockIdx.x;
    const int t = threadIdx.x;
    float v = 0.f;
    for (int ks = 0; ks < split; ++ks)
        v += P[((size_t)ks * Mdim + b) * NP + t];     // coalesced per ks
    float ss = v * v;
#pragma unroll
    for (int o = 32; o > 0; o >>= 1) ss += __shfl_down(ss, o, 64);
    __shared__ float wsum[5];
    __shared__ float scale;
    if ((t & 63) == 0) wsum[t >> 6] = ss;
    __syncthreads();
    if (t == 0) {
        float s = wsum[0] + wsum[1] + wsum[2] + wsum[3] + wsum[4];
        scale = 1.0f / (sqrtf(s) + 1e-7f);
    }
    __syncthreads();
    if (t < Ndim) out[(size_t)b * Ndim + t] = v * scale;
}

// ---------------- k3b: normalize only (atomic fallback path) ----------------
__global__ __launch_bounds__(320) void normalize_k(const float* __restrict__ Cacc,
                                                   float* __restrict__ out)
{
    const int b = blockIdx.x;
    const int t = threadIdx.x;
    float v = 0.f;
    if (t < Ndim) v = Cacc[(size_t)b * NP + t];
    float ss = v * v;
#pragma unroll
    for (int o = 32; o > 0; o >>= 1) ss += __shfl_down(ss, o, 64);
    __shared__ float wsum[5];
    __shared__ float scale;
    if ((t & 63) == 0) wsum[t >> 6] = ss;
    __syncthreads();
    if (t == 0) {
        float s = wsum[0] + wsum[1] + wsum[2] + wsum[3] + wsum[4];
        scale = 1.0f / (sqrtf(s) + 1e-7f);
    }
    __syncthreads();
    if (t < Ndim) out[(size_t)b * Ndim + t] = v * scale;
}

// ---------------- launch ----------------------------------------------------
extern "C" void kernel_launch(void* const* d_in, const int* in_sizes, int n_in,
                              void* d_out, int out_size, void* d_ws, size_t ws_size,
                              hipStream_t stream)
{
    const float* labels = (const float*)d_in[0];   // 1024 x 50000
    const float* weight = (const float*)d_in[1];   // 50000 x 300
    float* out = (float*)d_out;                    // 1024 x 300

    bf16* Wt = (bf16*)d_ws;                                   // 32.0 MB at offset 0
    const size_t wtBytes  = (size_t)NP * Kdim * sizeof(bf16); // 32,000,000
    float* aux = (float*)((char*)d_ws + wtBytes);
    const size_t perSplit = (size_t)Mdim * NP * sizeof(float); // 1.31 MB

    transpose_w<<<dim3((Kdim + TK - 1) / TK), dim3(256), 0, stream>>>(weight, Wt);

    if (ws_size >= wtBytes + 32 * perSplit) {
        // partial path, SPLIT=32 (SEGLEN=1600 = 50 x BK, grid 512 = 2 blocks/CU)
        gemm_kernel<32, 1600, false><<<dim3(MT * 32), dim3(512), 0, stream>>>(labels, Wt, aux);
        reduce_norm_k<<<dim3(Mdim), dim3(320), 0, stream>>>(aux, out, 32);
    } else if (ws_size >= wtBytes + 16 * perSplit) {
        // partial path, SPLIT=16 (SEGLEN=3136 = 98 x BK, grid 256)
        gemm_kernel<16, 3136, false><<<dim3(MT * 16), dim3(512), 0, stream>>>(labels, Wt, aux);
        reduce_norm_k<<<dim3(Mdim), dim3(320), 0, stream>>>(aux, out, 16);
    } else {
        // atomic fallback (needs 33.3 MB)
        hipMemsetAsync(aux, 0, perSplit, stream);
        gemm_kernel<32, 1600, true><<<dim3(MT * 32), dim3(512), 0, stream>>>(labels, Wt, aux);
        normalize_k<<<dim3(Mdim), dim3(320), 0, stream>>>(aux, out);
    }
}